// Round 1
// baseline (171.125 us; speedup 1.0000x reference)
//
#include <hip/hip_runtime.h>
#include <stdint.h>

typedef float f32x4 __attribute__((ext_vector_type(4)));
typedef __bf16 bf16x8 __attribute__((ext_vector_type(8)));
typedef unsigned short u16x8 __attribute__((ext_vector_type(8)));

// problem sizes
#define NIMG 32
#define CIN  256
#define HIN  56
#define WIN  56
#define HWIN 3136      // 56*56
#define COUT 256
#define HOUT 54
#define WOUT 54
#define HWOUT 2916     // 54*54
#define NPOS 93312     // 32*2916

// workspace layout
#define XT_BYTES   ((size_t)NIMG*HWIN*CIN*2)            // 51,380,224
#define WT_OFF     (XT_BYTES + 8192)                     // 8KB slack
#define WT_BYTES   ((size_t)9*8*256*32*2)                // 1,179,648
#define WS_NEED    (WT_OFF + WT_BYTES)

static __device__ __forceinline__ unsigned short f2bf(float f) {
    union { float f; uint32_t u; } v; v.f = f;
    return (unsigned short)((v.u + 0x7FFFu + ((v.u >> 16) & 1u)) >> 16);
}

static __device__ __forceinline__ void gload16(const void* g, void* l) {
    __builtin_amdgcn_global_load_lds(
        (const __attribute__((address_space(1))) void*)g,
        (__attribute__((address_space(3))) void*)l, 16, 0, 0);
}

// ---- W transform: [o][c][3][3] f32 -> bf16 +-1, blocked [k9][cc][256 o][32 c]
__global__ void wxform(const float* __restrict__ W, unsigned short* __restrict__ Wt) {
    int idx = blockIdx.x * 256 + threadIdx.x;   // 589824 total
    int cb = idx & 31;
    int o  = (idx >> 5) & 255;
    int cc = (idx >> 13) & 7;
    int k  = idx >> 16;
    int c  = cc * 32 + cb;
    float w = W[(size_t)(o * 256 + c) * 9 + k];
    Wt[idx] = (w >= 0.0f) ? (unsigned short)0x3F80 : (unsigned short)0xBF80;
}

// ---- X transform: [n][c][56][56] f32 -> [n][hw][c] bf16 (NHWC)
__global__ void xxform(const float* __restrict__ X, unsigned short* __restrict__ Xt) {
    __shared__ float tile[32][65];
    int bid = blockIdx.x;
    int hwc = bid % 49;
    int cc  = (bid / 49) & 7;
    int n   = bid / (49 * 8);
    int hw0 = hwc * 64;
    int c0  = cc * 32;
    int t = threadIdx.x;
    {
        int c = t >> 3;
        int w = (t & 7) * 8;
        const float* src = X + (size_t)(n * CIN + c0 + c) * HWIN + hw0 + w;
        float4 a = *(const float4*)src;
        float4 b = *(const float4*)(src + 4);
        tile[c][w + 0] = a.x; tile[c][w + 1] = a.y; tile[c][w + 2] = a.z; tile[c][w + 3] = a.w;
        tile[c][w + 4] = b.x; tile[c][w + 5] = b.y; tile[c][w + 6] = b.z; tile[c][w + 7] = b.w;
    }
    __syncthreads();
    {
        int w  = t >> 2;
        int cb = (t & 3) * 8;
        u16x8 v;
        #pragma unroll
        for (int j = 0; j < 8; ++j) v[j] = f2bf(tile[cb + j][w]);
        *(u16x8*)(Xt + (size_t)(n * HWIN + hw0 + w) * 256 + c0 + cb) = v;
    }
}

// ---- implicit GEMM: out[o][P] = sum_k Wb[o][k] * X[P][k], P = flat (n,h,w)
// block: 128 threads = 2 waves; tile 128 o x 64 P; BK=32
__global__ __launch_bounds__(128, 2)
void bconv_gemm(const unsigned short* __restrict__ Xt,
                const unsigned short* __restrict__ Wt,
                float* __restrict__ out) {
    __shared__ __align__(16) unsigned short lds[4096 + 2048]; // A [128][32], B [64][32]
    const int t    = threadIdx.x;
    const int wid  = t >> 6;
    const int lane = t & 63;
    const int l15  = lane & 15;
    const int lg   = lane >> 4;
    const uint32_t P0 = blockIdx.x * 64u;
    const int o0 = blockIdx.y * 128;

    // decode the two B rows this thread stages
    const int cb16 = (t & 3) * 8;
    uint32_t base0[2];
    #pragma unroll
    for (int r = 0; r < 2; ++r) {
        uint32_t P  = P0 + (t >> 2) + r * 32;
        uint32_t n  = P / (uint32_t)HWOUT;
        uint32_t rm = P - n * HWOUT;
        uint32_t ph = rm / 54u;
        uint32_t pw = rm - ph * 54u;
        base0[r] = n * HWIN + ph * 56u + pw;   // input hw-flat base (kh=kw=0)
    }

    f32x4 acc[4][4];
    #pragma unroll
    for (int m = 0; m < 4; ++m)
        #pragma unroll
        for (int nn = 0; nn < 4; ++nn)
            acc[m][nn] = (f32x4){0.f, 0.f, 0.f, 0.f};

    uint32_t aoff[4], boff[4];
    #pragma unroll
    for (int m = 0; m < 4; ++m)  aoff[m] = (uint32_t)((wid * 64 + m * 16 + l15) * 32 + lg * 8);
    #pragma unroll
    for (int nn = 0; nn < 4; ++nn) boff[nn] = (uint32_t)(4096 + (nn * 16 + l15) * 32 + lg * 8);

    for (int kh = 0; kh < 3; ++kh) {
        for (int c0 = 0; c0 < 8; ++c0) {
            #pragma unroll
            for (int kw = 0; kw < 3; ++kw) {
                const int k9 = kh * 3 + kw;
                // stage A: 8KB linear panel
                const unsigned short* aG = Wt + (size_t)(k9 * 8 + c0) * 8192 + o0 * 32 + t * 8;
                #pragma unroll
                for (int r = 0; r < 4; ++r)
                    gload16(aG + r * 1024, (unsigned short*)lds + r * 1024 + t * 8);
                // stage B: 4KB, per-lane gathered rows
                const uint32_t khw = (uint32_t)(kh * 56 + kw);
                #pragma unroll
                for (int r = 0; r < 2; ++r) {
                    const unsigned short* bG = Xt + ((size_t)(base0[r] + khw)) * 256 + c0 * 32 + cb16;
                    gload16(bG, (unsigned short*)lds + 4096 + r * 1024 + t * 8);
                }
                __syncthreads();
                bf16x8 af[4], bfr[4];
                #pragma unroll
                for (int m = 0; m < 4; ++m)
                    af[m] = __builtin_bit_cast(bf16x8, *(const u16x8*)(lds + aoff[m]));
                #pragma unroll
                for (int nn = 0; nn < 4; ++nn)
                    bfr[nn] = __builtin_bit_cast(bf16x8, *(const u16x8*)(lds + boff[nn]));
                #pragma unroll
                for (int m = 0; m < 4; ++m)
                    #pragma unroll
                    for (int nn = 0; nn < 4; ++nn)
                        acc[m][nn] = __builtin_amdgcn_mfma_f32_16x16x32_bf16(
                            af[m], bfr[nn], acc[m][nn], 0, 0, 0);
                __syncthreads();
            }
        }
    }

    // epilogue: D col = l15 -> P, row = lg*4+r -> o
    #pragma unroll
    for (int nn = 0; nn < 4; ++nn) {
        uint32_t P  = P0 + nn * 16 + l15;
        uint32_t n  = P / (uint32_t)HWOUT;
        uint32_t rm = P - n * HWOUT;
        float* obase = out + (size_t)(n * 256u + o0 + wid * 64) * HWOUT + rm;
        #pragma unroll
        for (int m = 0; m < 4; ++m)
            #pragma unroll
            for (int r = 0; r < 4; ++r)
                obase[(size_t)(m * 16 + lg * 4 + r) * HWOUT] = acc[m][nn][r];
    }
}

// ---- slow correct fallback (only if ws too small)
__global__ void bconv_fallback(const float* __restrict__ X, const float* __restrict__ W,
                               float* __restrict__ out) {
    size_t idx = (size_t)blockIdx.x * 256 + threadIdx.x;  // 23,887,872 exact
    int ow = (int)(idx % 54);
    int oh = (int)((idx / 54) % 54);
    int o  = (int)((idx / 2916) % 256);
    int n  = (int)(idx / 746496);
    float s = 0.f;
    for (int c = 0; c < 256; ++c) {
        const float* xr = X + ((size_t)(n * 256 + c) * 56 + oh) * 56 + ow;
        const float* wr = W + (size_t)(o * 256 + c) * 9;
        #pragma unroll
        for (int kh = 0; kh < 3; ++kh)
            #pragma unroll
            for (int kw = 0; kw < 3; ++kw) {
                float w = wr[kh * 3 + kw];
                float x = xr[kh * 56 + kw];
                s += (w >= 0.f) ? x : -x;
            }
    }
    out[idx] = s;
}

extern "C" void kernel_launch(void* const* d_in, const int* in_sizes, int n_in,
                              void* d_out, int out_size, void* d_ws, size_t ws_size,
                              hipStream_t stream) {
    const float* X = (const float*)d_in[0];
    const float* W = (const float*)d_in[1];
    float* out = (float*)d_out;

    if (ws_size < WS_NEED) {
        bconv_fallback<<<93312, 256, 0, stream>>>(X, W, out);
        return;
    }
    unsigned short* Xt = (unsigned short*)d_ws;
    unsigned short* Wt = (unsigned short*)((char*)d_ws + WT_OFF);

    wxform<<<2304, 256, 0, stream>>>(W, Wt);
    xxform<<<12544, 256, 0, stream>>>(X, Xt);

    dim3 grid(1458, 2);
    bconv_gemm<<<grid, 128, 0, stream>>>(Xt, Wt, out);
}

// Round 2
// 163.422 us; speedup vs baseline: 1.0471x; 1.0471x over previous
//
#include <hip/hip_runtime.h>
#include <stdint.h>

typedef float f32x4 __attribute__((ext_vector_type(4)));
typedef __bf16 bf16x8 __attribute__((ext_vector_type(8)));
typedef unsigned short u16x8 __attribute__((ext_vector_type(8)));

// problem sizes
#define NIMG 32
#define CIN  256
#define HWIN 3136      // 56*56
#define COUT 256
#define HWOUT 2916     // 54*54
#define NPOS 93312     // 32*2916

// workspace layout
#define XT_BYTES   ((size_t)NIMG*HWIN*CIN*2)            // 51,380,224
#define WT_OFF     (XT_BYTES + 8192)
#define WT_BYTES   ((size_t)9*4*2*128*64*2)             // 1,179,648
#define WS_NEED    (WT_OFF + WT_BYTES)

static __device__ __forceinline__ unsigned short f2bf(float f) {
    union { float f; uint32_t u; } v; v.f = f;
    return (unsigned short)((v.u + 0x7FFFu + ((v.u >> 16) & 1u)) >> 16);
}

static __device__ __forceinline__ void gload16(const void* g, void* l) {
    __builtin_amdgcn_global_load_lds(
        (const __attribute__((address_space(1))) void*)g,
        (__attribute__((address_space(3))) void*)l, 16, 0, 0);
}

static __device__ __forceinline__ uint32_t lds_a(const void* p) {
    return (uint32_t)(uintptr_t)(__attribute__((address_space(3))) const void*)p;
}

static __device__ __forceinline__ u16x8 ldsr(uint32_t addr) {
    u16x8 r;
    asm volatile("ds_read_b128 %0, %1" : "=v"(r) : "v"(addr));
    return r;
}

#define BAR()   __builtin_amdgcn_s_barrier()
#define LGKM0() do { asm volatile("s_waitcnt lgkmcnt(0)" ::: "memory"); \
                     __builtin_amdgcn_sched_barrier(0); } while (0)
#define VM2()   asm volatile("s_waitcnt vmcnt(2)" ::: "memory")
#define VM6()   asm volatile("s_waitcnt vmcnt(6)" ::: "memory")
#define VM0()   asm volatile("s_waitcnt vmcnt(0)" ::: "memory")
#define PRIO1() __builtin_amdgcn_s_setprio(1)
#define PRIO0() __builtin_amdgcn_s_setprio(0)

#define MF(a_, b_, c_) __builtin_amdgcn_mfma_f32_16x16x32_bf16( \
    __builtin_bit_cast(bf16x8, a_), __builtin_bit_cast(bf16x8, b_), c_, 0, 0, 0)

#define QUAD(aa, ab, m0_, m1_, c0_, c1_, c2_, c3_)         \
    acc[m0_][0] = MF(aa, c0_, acc[m0_][0]);                \
    acc[m0_][1] = MF(aa, c1_, acc[m0_][1]);                \
    acc[m0_][2] = MF(aa, c2_, acc[m0_][2]);                \
    acc[m0_][3] = MF(aa, c3_, acc[m0_][3]);                \
    acc[m1_][0] = MF(ab, c0_, acc[m1_][0]);                \
    acc[m1_][1] = MF(ab, c1_, acc[m1_][1]);                \
    acc[m1_][2] = MF(ab, c2_, acc[m1_][2]);                \
    acc[m1_][3] = MF(ab, c3_, acc[m1_][3]);

// ---- W transform: [o][c][3][3] f32 -> bf16 +-1, blocked [k9][cc64][ob][128 o][64 c]
__global__ void wxform(const float* __restrict__ W, unsigned short* __restrict__ Wt) {
    int idx = blockIdx.x * 256 + threadIdx.x;   // 589824 total
    int c6 = idx & 63;
    int o7 = (idx >> 6) & 127;
    int ob = (idx >> 13) & 1;
    int cc = (idx >> 14) & 3;
    int k9 = idx >> 16;
    int o = ob * 128 + o7;
    int c = cc * 64 + c6;
    float w = W[(size_t)(o * 256 + c) * 9 + k9];
    Wt[idx] = (w >= 0.0f) ? (unsigned short)0x3F80 : (unsigned short)0xBF80;
}

// ---- X transform: [n][c][56][56] f32 -> [n][hw][c] bf16 (NHWC)
__global__ void xxform(const float* __restrict__ X, unsigned short* __restrict__ Xt) {
    __shared__ float tile[32][65];
    int bid = blockIdx.x;
    int hwc = bid % 49;
    int cc  = (bid / 49) & 7;
    int n   = bid / (49 * 8);
    int hw0 = hwc * 64;
    int c0  = cc * 32;
    int t = threadIdx.x;
    {
        int c = t >> 3;
        int w = (t & 7) * 8;
        const float* src = X + (size_t)(n * CIN + c0 + c) * HWIN + hw0 + w;
        float4 a = *(const float4*)src;
        float4 b = *(const float4*)(src + 4);
        tile[c][w + 0] = a.x; tile[c][w + 1] = a.y; tile[c][w + 2] = a.z; tile[c][w + 3] = a.w;
        tile[c][w + 4] = b.x; tile[c][w + 5] = b.y; tile[c][w + 6] = b.z; tile[c][w + 7] = b.w;
    }
    __syncthreads();
    {
        int w  = t >> 2;
        int cb = (t & 3) * 8;
        u16x8 v;
        #pragma unroll
        for (int j = 0; j < 8; ++j) v[j] = f2bf(tile[cb + j][w]);
        *(u16x8*)(Xt + (size_t)(n * HWIN + hw0 + w) * 256 + c0 + cb) = v;
    }
}

// ---- 8-phase implicit GEMM: out[o][P] = sum_k Wb[o][k] * X[P][k]
// BM=128 (o), BN=256 (pos), BK=64; 512 thr = 8 waves (2M x 4N), wave tile 64x64
// LDS: 2 bufs x (A 16KB + B 32KB) = 96KB; XOR (row&7) swizzle both-sides
__global__ __launch_bounds__(512, 2)
void bconv_gemm(const unsigned short* __restrict__ Xt,
                const unsigned short* __restrict__ Wt,
                float* __restrict__ out) {
    __shared__ __align__(16) char smem[98304];

    const int t    = threadIdx.x;
    const int wid  = t >> 6;
    const int lane = t & 63;
    const int l15  = lane & 15;
    const int lg   = lane >> 4;
    const int wr   = wid >> 2;       // 0..1 (M)
    const int wc   = wid & 3;        // 0..3 (N)
    const int ob   = blockIdx.x;     // 0..1 (o block)
    const uint32_t P0 = blockIdx.y * 256u;

    // staging constants
    const uint32_t colx = (uint32_t)(((t & 7) ^ ((t >> 3) & 7)) << 3);  // elements
    const uint32_t aG   = (uint32_t)(t >> 3) * 64u + colx;

    // B gather bases: 4 rows per thread (r*64 + t/8)
    uint32_t base0[4];
    #pragma unroll
    for (int r = 0; r < 4; ++r) {
        uint32_t pos = P0 + (uint32_t)(r * 64 + (t >> 3));
        if (pos >= NPOS) pos = NPOS - 1;
        uint32_t ni = pos / (uint32_t)HWOUT;
        uint32_t rm = pos - ni * HWOUT;
        uint32_t ph = rm / 54u;
        uint32_t pw = rm - ph * 54u;
        base0[r] = ni * HWIN + ph * 56u + pw;
    }

    // ds_read offsets
    const uint32_t x7  = (uint32_t)(l15 & 7);
    const uint32_t ck0 = ((((uint32_t)lg) ^ x7) << 4);
    const uint32_t ck1 = (((4u | (uint32_t)lg) ^ x7) << 4);
    const uint32_t ar0 = (uint32_t)(wr * 64 + 0 * 16 + l15) * 128u;
    const uint32_t ar1 = (uint32_t)(wr * 64 + 1 * 16 + l15) * 128u;
    const uint32_t ar2 = (uint32_t)(wr * 64 + 2 * 16 + l15) * 128u;
    const uint32_t ar3 = (uint32_t)(wr * 64 + 3 * 16 + l15) * 128u;
    const uint32_t br0 = 16384u + (uint32_t)(wc * 64 + 0 * 16 + l15) * 128u;
    const uint32_t br1 = 16384u + (uint32_t)(wc * 64 + 1 * 16 + l15) * 128u;
    const uint32_t br2 = 16384u + (uint32_t)(wc * 64 + 2 * 16 + l15) * 128u;
    const uint32_t br3 = 16384u + (uint32_t)(wc * 64 + 3 * 16 + l15) * 128u;

    const uint32_t E = lds_a(smem);
    const uint32_t O = E + 49152u;

    f32x4 acc[4][4];
    #pragma unroll
    for (int m = 0; m < 4; ++m)
        #pragma unroll
        for (int n = 0; n < 4; ++n)
            acc[m][n] = (f32x4){0.f, 0.f, 0.f, 0.f};

    // stage helpers (kt in [0,36): k9 = kt>>2, cc = kt&3)
    auto STAGE_A = [&](uint32_t bufoff, int kt) {
        int k9 = kt >> 2, cc = kt & 3;
        const unsigned short* p = Wt + ((size_t)(((k9 << 2) | cc) * 2 + ob)) * 8192 + aG;
        gload16(p,        smem + bufoff + (size_t)t * 16);
        gload16(p + 4096, smem + bufoff + 8192 + (size_t)t * 16);
    };
    auto STAGE_B2 = [&](uint32_t bufoff, int kt, int r0) {
        int k9 = kt >> 2, cc = kt & 3;
        int kh = k9 / 3, kw = k9 - kh * 3;
        uint32_t khw = (uint32_t)(kh * 56 + kw);
        #pragma unroll
        for (int r = r0; r < r0 + 2; ++r) {
            const unsigned short* p = Xt + (size_t)(base0[r] + khw) * 256 + (uint32_t)cc * 64u + colx;
            gload16(p, smem + bufoff + 16384 + (size_t)r * 8192 + (size_t)t * 16);
        }
    };

    // prologue: tiles 0 -> E, 1 -> O
    STAGE_A(0, 0);      STAGE_B2(0, 0, 0);      STAGE_B2(0, 0, 2);
    STAGE_A(49152u, 1); STAGE_B2(49152u, 1, 0); STAGE_B2(49152u, 1, 2);
    VM6();
    BAR();

    u16x8 a00, a01, a10, a11;
    u16x8 b00, b10, b20, b30, b01, b11, b21, b31;

    auto ITER = [&](int kt, bool pf) {
        // P1: bufE A m0,m1 (k0,k1) + B n0-3 (k0)
        a00 = ldsr(E + ar0 + ck0); a01 = ldsr(E + ar0 + ck1);
        a10 = ldsr(E + ar1 + ck0); a11 = ldsr(E + ar1 + ck1);
        b00 = ldsr(E + br0 + ck0); b10 = ldsr(E + br1 + ck0);
        b20 = ldsr(E + br2 + ck0); b30 = ldsr(E + br3 + ck0);
        BAR(); LGKM0(); PRIO1();
        QUAD(a00, a10, 0, 1, b00, b10, b20, b30);
        PRIO0(); BAR();
        // P2: bufE B n0-3 (k1)
        b01 = ldsr(E + br0 + ck1); b11 = ldsr(E + br1 + ck1);
        b21 = ldsr(E + br2 + ck1); b31 = ldsr(E + br3 + ck1);
        BAR(); LGKM0(); PRIO1();
        QUAD(a01, a11, 0, 1, b01, b11, b21, b31);
        PRIO0(); BAR();
        // P3: bufE A m2,m3 (k0,k1)
        a00 = ldsr(E + ar2 + ck0); a01 = ldsr(E + ar2 + ck1);
        a10 = ldsr(E + ar3 + ck0); a11 = ldsr(E + ar3 + ck1);
        BAR(); LGKM0(); PRIO1();
        QUAD(a00, a10, 2, 3, b00, b10, b20, b30);
        PRIO0(); BAR();
        // P4: stage A(kt+2 -> E); counted vmcnt; MFMA m23 k1
        if (pf) { STAGE_A(0, kt + 2); VM2(); } else { VM0(); }
        BAR(); PRIO1();
        QUAD(a01, a11, 2, 3, b01, b11, b21, b31);
        PRIO0(); BAR();
        // P5: bufO A m0,m1 + B k0; stage B01(kt+2 -> E)
        a00 = ldsr(O + ar0 + ck0); a01 = ldsr(O + ar0 + ck1);
        a10 = ldsr(O + ar1 + ck0); a11 = ldsr(O + ar1 + ck1);
        b00 = ldsr(O + br0 + ck0); b10 = ldsr(O + br1 + ck0);
        b20 = ldsr(O + br2 + ck0); b30 = ldsr(O + br3 + ck0);
        if (pf) STAGE_B2(0, kt + 2, 0);
        BAR(); LGKM0(); PRIO1();
        QUAD(a00, a10, 0, 1, b00, b10, b20, b30);
        PRIO0(); BAR();
        // P6: bufO B k1; stage B23(kt+2 -> E)
        b01 = ldsr(O + br0 + ck1); b11 = ldsr(O + br1 + ck1);
        b21 = ldsr(O + br2 + ck1); b31 = ldsr(O + br3 + ck1);
        if (pf) STAGE_B2(0, kt + 2, 2);
        BAR(); LGKM0(); PRIO1();
        QUAD(a01, a11, 0, 1, b01, b11, b21, b31);
        PRIO0(); BAR();
        // P7: bufO A m2,m3
        a00 = ldsr(O + ar2 + ck0); a01 = ldsr(O + ar2 + ck1);
        a10 = ldsr(O + ar3 + ck0); a11 = ldsr(O + ar3 + ck1);
        BAR(); LGKM0(); PRIO1();
        QUAD(a00, a10, 2, 3, b00, b10, b20, b30);
        PRIO0(); BAR();
        // P8: stage all(kt+3 -> O); counted vmcnt; MFMA m23 k1
        if (pf) {
            STAGE_A(49152u, kt + 3);
            STAGE_B2(49152u, kt + 3, 0);
            STAGE_B2(49152u, kt + 3, 2);
            VM6();
        } else {
            VM0();
        }
        BAR(); PRIO1();
        QUAD(a01, a11, 2, 3, b01, b11, b21, b31);
        PRIO0(); BAR();
    };

    for (int kt = 0; kt < 34; kt += 2) ITER(kt, true);
    ITER(34, false);

    // epilogue: C/D col = l15 -> P, row = lg*4+r -> o
    const int orow0 = ob * 128 + wr * 64;
    #pragma unroll
    for (int n = 0; n < 4; ++n) {
        uint32_t P = P0 + (uint32_t)(wc * 64 + n * 16 + l15);
        if (P < NPOS) {
            uint32_t ni = P / (uint32_t)HWOUT;
            uint32_t rm = P - ni * HWOUT;
            float* ob_ = out + (size_t)(ni * 256u + orow0) * HWOUT + rm;
            #pragma unroll
            for (int m = 0; m < 4; ++m)
                #pragma unroll
                for (int r = 0; r < 4; ++r)
                    ob_[(size_t)(m * 16 + lg * 4 + r) * HWOUT] = acc[m][n][r];
        }
    }
}

// ---- slow correct fallback (only if ws too small)
__global__ void bconv_fallback(const float* __restrict__ X, const float* __restrict__ W,
                               float* __restrict__ out) {
    size_t idx = (size_t)blockIdx.x * 256 + threadIdx.x;
    int ow = (int)(idx % 54);
    int oh = (int)((idx / 54) % 54);
    int o  = (int)((idx / 2916) % 256);
    int n  = (int)(idx / 746496);
    float s = 0.f;
    for (int c = 0; c < 256; ++c) {
        const float* xr = X + ((size_t)(n * 256 + c) * 56 + oh) * 56 + ow;
        const float* wr = W + (size_t)(o * 256 + c) * 9;
        #pragma unroll
        for (int kh = 0; kh < 3; ++kh)
            #pragma unroll
            for (int kw = 0; kw < 3; ++kw) {
                float w = wr[kh * 3 + kw];
                float x = xr[kh * 56 + kw];
                s += (w >= 0.f) ? x : -x;
            }
    }
    out[idx] = s;
}

extern "C" void kernel_launch(void* const* d_in, const int* in_sizes, int n_in,
                              void* d_out, int out_size, void* d_ws, size_t ws_size,
                              hipStream_t stream) {
    const float* X = (const float*)d_in[0];
    const float* W = (const float*)d_in[1];
    float* out = (float*)d_out;

    if (ws_size < WS_NEED) {
        bconv_fallback<<<93312, 256, 0, stream>>>(X, W, out);
        return;
    }
    unsigned short* Xt = (unsigned short*)d_ws;
    unsigned short* Wt = (unsigned short*)((char*)d_ws + WT_OFF);

    wxform<<<2304, 256, 0, stream>>>(W, Wt);
    xxform<<<12544, 256, 0, stream>>>(X, Xt);

    dim3 grid(2, 365);
    bconv_gemm<<<grid, 512, 0, stream>>>(Xt, Wt, out);
}

// Round 3
// 147.031 us; speedup vs baseline: 1.1639x; 1.1115x over previous
//
#include <hip/hip_runtime.h>
#include <stdint.h>

typedef float f32x4 __attribute__((ext_vector_type(4)));
typedef __bf16 bf16x8 __attribute__((ext_vector_type(8)));
typedef unsigned short u16x8 __attribute__((ext_vector_type(8)));

// problem sizes
#define NIMG 32
#define CIN  256
#define HWIN 3136      // 56*56
#define COUT 256
#define HWOUT 2916     // 54*54
#define NPOS 93312     // 32*2916 = 729*128

// workspace layout
#define XT_BYTES   ((size_t)NIMG*HWIN*CIN*2)            // 51,380,224
#define WT_OFF     (XT_BYTES + 8192)
#define WT_BYTES   ((size_t)36*2*128*64*2)              // 1,179,648
#define WS_NEED    (WT_OFF + WT_BYTES)

static __device__ __forceinline__ unsigned short f2bf(float f) {
    union { float f; uint32_t u; } v; v.f = f;
    return (unsigned short)((v.u + 0x7FFFu + ((v.u >> 16) & 1u)) >> 16);
}

static __device__ __forceinline__ void gload16(const void* g, void* l) {
    __builtin_amdgcn_global_load_lds(
        (const __attribute__((address_space(1))) void*)g,
        (__attribute__((address_space(3))) void*)l, 16, 0, 0);
}

static __device__ __forceinline__ uint32_t lds_a(const void* p) {
    return (uint32_t)(uintptr_t)(__attribute__((address_space(3))) const void*)p;
}

static __device__ __forceinline__ u16x8 ldsr(uint32_t addr) {
    u16x8 r;
    asm volatile("ds_read_b128 %0, %1" : "=v"(r) : "v"(addr));
    return r;
}

#define BAR()   __builtin_amdgcn_s_barrier()
#define LGKM0() do { asm volatile("s_waitcnt lgkmcnt(0)" ::: "memory"); \
                     __builtin_amdgcn_sched_barrier(0); } while (0)
#define VM8()   asm volatile("s_waitcnt vmcnt(8)" ::: "memory")
#define VM0()   asm volatile("s_waitcnt vmcnt(0)" ::: "memory")
#define PRIO1() __builtin_amdgcn_s_setprio(1)
#define PRIO0() __builtin_amdgcn_s_setprio(0)

#define MF(a_, b_, c_) __builtin_amdgcn_mfma_f32_16x16x32_bf16( \
    __builtin_bit_cast(bf16x8, a_), __builtin_bit_cast(bf16x8, b_), c_, 0, 0, 0)

// 16 MFMA: full 4m x 4n for one k-half
#define M16()                                              \
    acc[0][0] = MF(a0, b0, acc[0][0]);                     \
    acc[1][0] = MF(a1, b0, acc[1][0]);                     \
    acc[2][0] = MF(a2, b0, acc[2][0]);                     \
    acc[3][0] = MF(a3, b0, acc[3][0]);                     \
    acc[0][1] = MF(a0, b1, acc[0][1]);                     \
    acc[1][1] = MF(a1, b1, acc[1][1]);                     \
    acc[2][1] = MF(a2, b1, acc[2][1]);                     \
    acc[3][1] = MF(a3, b1, acc[3][1]);                     \
    acc[0][2] = MF(a0, b2, acc[0][2]);                     \
    acc[1][2] = MF(a1, b2, acc[1][2]);                     \
    acc[2][2] = MF(a2, b2, acc[2][2]);                     \
    acc[3][2] = MF(a3, b2, acc[3][2]);                     \
    acc[0][3] = MF(a0, b3, acc[0][3]);                     \
    acc[1][3] = MF(a1, b3, acc[1][3]);                     \
    acc[2][3] = MF(a2, b3, acc[2][3]);                     \
    acc[3][3] = MF(a3, b3, acc[3][3]);

// ---- W transform: [o][c][3][3] f32 -> bf16 +-1, blocked [k9][cc64][ob][128 o][64 c]
__global__ void wxform(const float* __restrict__ W, unsigned short* __restrict__ Wt) {
    int idx = blockIdx.x * 256 + threadIdx.x;   // 589824 total
    int c6 = idx & 63;
    int o7 = (idx >> 6) & 127;
    int ob = (idx >> 13) & 1;
    int cc = (idx >> 14) & 3;
    int k9 = idx >> 16;
    int o = ob * 128 + o7;
    int c = cc * 64 + c6;
    float w = W[(size_t)(o * 256 + c) * 9 + k9];
    Wt[idx] = (w >= 0.0f) ? (unsigned short)0x3F80 : (unsigned short)0xBF80;
}

// ---- X transform: [n][c][56][56] f32 -> [n][hw][c] bf16 (NHWC)
__global__ void xxform(const float* __restrict__ X, unsigned short* __restrict__ Xt) {
    __shared__ float tile[32][65];
    int bid = blockIdx.x;
    int hwc = bid % 49;
    int cc  = (bid / 49) & 7;
    int n   = bid / (49 * 8);
    int hw0 = hwc * 64;
    int c0  = cc * 32;
    int t = threadIdx.x;
    {
        int c = t >> 3;
        int w = (t & 7) * 8;
        const float* src = X + (size_t)(n * CIN + c0 + c) * HWIN + hw0 + w;
        float4 a = *(const float4*)src;
        float4 b = *(const float4*)(src + 4);
        tile[c][w + 0] = a.x; tile[c][w + 1] = a.y; tile[c][w + 2] = a.z; tile[c][w + 3] = a.w;
        tile[c][w + 4] = b.x; tile[c][w + 5] = b.y; tile[c][w + 6] = b.z; tile[c][w + 7] = b.w;
    }
    __syncthreads();
    {
        int w  = t >> 2;
        int cb = (t & 3) * 8;
        u16x8 v;
        #pragma unroll
        for (int j = 0; j < 8; ++j) v[j] = f2bf(tile[cb + j][w]);
        *(u16x8*)(Xt + (size_t)(n * HWIN + hw0 + w) * 256 + c0 + cb) = v;
    }
}

// ---- 4-phase implicit GEMM, 2 blocks/CU: out[o][P] = sum_k Wb[o][k] * X[P][k]
// BM=128 (o), BN=128 (pos), BK=64; 256 thr = 4 waves (2M x 2N), wave tile 64x64
// LDS: 2 bufs x (A 16KB + B 16KB) = 64KB -> 2 independent blocks per CU
__global__ __launch_bounds__(256, 2)
void bconv_gemm(const unsigned short* __restrict__ Xt,
                const unsigned short* __restrict__ Wt,
                float* __restrict__ out) {
    __shared__ __align__(16) char smem[65536];

    const int t    = threadIdx.x;
    const int wid  = t >> 6;
    const int lane = t & 63;
    const int l15  = lane & 15;
    const int lg   = lane >> 4;
    const int wr   = wid >> 1;       // 0..1 (M)
    const int wc   = wid & 1;        // 0..1 (N)
    const int ob   = blockIdx.x;     // 0..1 (o block)
    const uint32_t P0 = blockIdx.y * 128u;

    // staging constants (XOR swizzle baked into the GLOBAL source column)
    const uint32_t colxB = (uint32_t)(((t & 7) ^ ((t >> 3) & 7)) << 4);  // bytes
    const uint32_t rowt  = (uint32_t)(t >> 3);                           // 0..31

    // A per-thread byte base: panel row (r*32 + rowt), swizzled col
    const char* pA0 = (const char*)Wt + (size_t)ob * 16384 + rowt * 128 + colxB;

    // B gather byte bases: 4 rows per thread (r*32 + rowt)
    const char* bB[4];
    #pragma unroll
    for (int r = 0; r < 4; ++r) {
        uint32_t pos = P0 + (uint32_t)(r * 32) + rowt;
        uint32_t ni = pos / (uint32_t)HWOUT;
        uint32_t rm = pos - ni * HWOUT;
        uint32_t ph = rm / 54u;
        uint32_t pw = rm - ph * 54u;
        bB[r] = (const char*)Xt + (size_t)(ni * HWIN + ph * 56u + pw) * 512 + colxB;
    }

    // ds_read offsets (swizzled read side)
    const uint32_t x7  = (uint32_t)(l15 & 7);
    const uint32_t ck0 = ((((uint32_t)lg) ^ x7) << 4);
    const uint32_t ck1 = (((4u | (uint32_t)lg) ^ x7) << 4);
    const uint32_t ar0 = (uint32_t)(wr * 64 + 0 * 16 + l15) * 128u;
    const uint32_t ar1 = (uint32_t)(wr * 64 + 1 * 16 + l15) * 128u;
    const uint32_t ar2 = (uint32_t)(wr * 64 + 2 * 16 + l15) * 128u;
    const uint32_t ar3 = (uint32_t)(wr * 64 + 3 * 16 + l15) * 128u;
    const uint32_t br0 = 16384u + (uint32_t)(wc * 64 + 0 * 16 + l15) * 128u;
    const uint32_t br1 = 16384u + (uint32_t)(wc * 64 + 1 * 16 + l15) * 128u;
    const uint32_t br2 = 16384u + (uint32_t)(wc * 64 + 2 * 16 + l15) * 128u;
    const uint32_t br3 = 16384u + (uint32_t)(wc * 64 + 3 * 16 + l15) * 128u;

    const uint32_t E = lds_a(smem);
    const uint32_t O = E + 32768u;

    f32x4 acc[4][4];
    #pragma unroll
    for (int m = 0; m < 4; ++m)
        #pragma unroll
        for (int n = 0; n < 4; ++n)
            acc[m][n] = (f32x4){0.f, 0.f, 0.f, 0.f};

    auto STAGE_A = [&](uint32_t bufoff, int kt) {
        const char* p = pA0 + (uint32_t)kt * 32768u;     // kt*32768: uniform SALU mul
        #pragma unroll
        for (int r = 0; r < 4; ++r)
            gload16(p + r * 4096, smem + bufoff + r * 4096 + (size_t)t * 16);
    };
    auto STAGE_B = [&](uint32_t bufoff, uint32_t koff) {
        #pragma unroll
        for (int r = 0; r < 4; ++r)
            gload16(bB[r] + koff, smem + bufoff + 16384 + r * 4096 + (size_t)t * 16);
    };

    // wave-uniform k-offset trackers for B staging: koff = khw*512 + cc*128
    // kt = k9*4 + cc, khw(k9) = (k9/3)*56 + k9%3
    uint32_t ccE = 2, k3E = 0, koffE = 256;   // tracks tile kt+2 (starts at 2)
    uint32_t ccO = 3, k3O = 0, koffO = 384;   // tracks tile kt+3 (starts at 3)
    auto adv2 = [](uint32_t& cc, uint32_t& k3, uint32_t& koff) {
        #pragma unroll
        for (int s = 0; s < 2; ++s) {
            if (cc == 3) { cc = 0; koff += ((k3 == 2) ? 54u : 1u) * 512u - 384u; k3 = (k3 == 2) ? 0u : k3 + 1u; }
            else         { cc++; koff += 128u; }
        }
    };

    // prologue: tile 0 -> E, tile 1 -> O
    STAGE_A(0, 0);      STAGE_B(0, 0);
    STAGE_A(32768u, 1); STAGE_B(32768u, 128);
    VM8();   // E's 8 complete (O's 8 may remain in flight)
    BAR();

    u16x8 a0, a1, a2, a3, b0, b1, b2, b3;

    auto ITER = [&](int kt, bool pf) {
        // P1: E k0
        a0 = ldsr(E + ar0 + ck0); a1 = ldsr(E + ar1 + ck0);
        a2 = ldsr(E + ar2 + ck0); a3 = ldsr(E + ar3 + ck0);
        b0 = ldsr(E + br0 + ck0); b1 = ldsr(E + br1 + ck0);
        b2 = ldsr(E + br2 + ck0); b3 = ldsr(E + br3 + ck0);
        BAR(); LGKM0(); PRIO1();
        M16();
        PRIO0(); BAR();
        // P2: E k1; certify O (prev-P4's loads, ~4 phases old)
        a0 = ldsr(E + ar0 + ck1); a1 = ldsr(E + ar1 + ck1);
        a2 = ldsr(E + ar2 + ck1); a3 = ldsr(E + ar3 + ck1);
        b0 = ldsr(E + br0 + ck1); b1 = ldsr(E + br1 + ck1);
        b2 = ldsr(E + br2 + ck1); b3 = ldsr(E + br3 + ck1);
        VM0();
        BAR(); LGKM0(); PRIO1();
        M16();
        PRIO0(); BAR();
        // P3: O k0 reads; stage kt+2 -> E (E fully consumed: all waves drained in P2)
        a0 = ldsr(O + ar0 + ck0); a1 = ldsr(O + ar1 + ck0);
        a2 = ldsr(O + ar2 + ck0); a3 = ldsr(O + ar3 + ck0);
        b0 = ldsr(O + br0 + ck0); b1 = ldsr(O + br1 + ck0);
        b2 = ldsr(O + br2 + ck0); b3 = ldsr(O + br3 + ck0);
        if (pf) { STAGE_A(0, kt + 2); STAGE_B(0, koffE); }
        BAR(); LGKM0(); PRIO1();
        M16();
        PRIO0(); BAR();
        // P4: O k1 reads; stage kt+3 -> O; counted wait drains E-stage (P3's 8)
        a0 = ldsr(O + ar0 + ck1); a1 = ldsr(O + ar1 + ck1);
        a2 = ldsr(O + ar2 + ck1); a3 = ldsr(O + ar3 + ck1);
        b0 = ldsr(O + br0 + ck1); b1 = ldsr(O + br1 + ck1);
        b2 = ldsr(O + br2 + ck1); b3 = ldsr(O + br3 + ck1);
        if (pf) { STAGE_A(32768u, kt + 3); STAGE_B(32768u, koffO); VM8(); }
        else    { VM0(); }
        BAR(); LGKM0(); PRIO1();
        M16();
        PRIO0(); BAR();
        if (pf) { adv2(ccE, k3E, koffE); adv2(ccO, k3O, koffO); }
    };

    for (int kt = 0; kt < 34; kt += 2) ITER(kt, true);
    ITER(34, false);

    // epilogue: C/D col = l15 -> P, row = lg*4+r -> o   (93312 = 729*128: no bounds needed)
    const int orow0 = ob * 128 + wr * 64;
    #pragma unroll
    for (int n = 0; n < 4; ++n) {
        uint32_t P = P0 + (uint32_t)(wc * 64 + n * 16 + l15);
        uint32_t ni = P / (uint32_t)HWOUT;
        uint32_t rm = P - ni * HWOUT;
        float* ob_ = out + (size_t)(ni * 256u + orow0) * HWOUT + rm;
        #pragma unroll
        for (int m = 0; m < 4; ++m)
            #pragma unroll
            for (int r = 0; r < 4; ++r)
                ob_[(size_t)(m * 16 + lg * 4 + r) * HWOUT] = acc[m][n][r];
    }
}

// ---- slow correct fallback (only if ws too small)
__global__ void bconv_fallback(const float* __restrict__ X, const float* __restrict__ W,
                               float* __restrict__ out) {
    size_t idx = (size_t)blockIdx.x * 256 + threadIdx.x;
    int ow = (int)(idx % 54);
    int oh = (int)((idx / 54) % 54);
    int o  = (int)((idx / 2916) % 256);
    int n  = (int)(idx / 746496);
    float s = 0.f;
    for (int c = 0; c < 256; ++c) {
        const float* xr = X + ((size_t)(n * 256 + c) * 56 + oh) * 56 + ow;
        const float* wr = W + (size_t)(o * 256 + c) * 9;
        #pragma unroll
        for (int kh = 0; kh < 3; ++kh)
            #pragma unroll
            for (int kw = 0; kw < 3; ++kw) {
                float w = wr[kh * 3 + kw];
                float x = xr[kh * 56 + kw];
                s += (w >= 0.f) ? x : -x;
            }
    }
    out[idx] = s;
}

extern "C" void kernel_launch(void* const* d_in, const int* in_sizes, int n_in,
                              void* d_out, int out_size, void* d_ws, size_t ws_size,
                              hipStream_t stream) {
    const float* X = (const float*)d_in[0];
    const float* W = (const float*)d_in[1];
    float* out = (float*)d_out;

    if (ws_size < WS_NEED) {
        bconv_fallback<<<93312, 256, 0, stream>>>(X, W, out);
        return;
    }
    unsigned short* Xt = (unsigned short*)d_ws;
    unsigned short* Wt = (unsigned short*)((char*)d_ws + WT_OFF);

    wxform<<<2304, 256, 0, stream>>>(W, Wt);
    xxform<<<12544, 256, 0, stream>>>(X, Xt);

    dim3 grid(2, 729);
    bconv_gemm<<<grid, 256, 0, stream>>>(Xt, Wt, out);
}

// Round 4
// 145.876 us; speedup vs baseline: 1.1731x; 1.0079x over previous
//
#include <hip/hip_runtime.h>
#include <stdint.h>

typedef float f32x4 __attribute__((ext_vector_type(4)));
typedef __bf16 bf16x8 __attribute__((ext_vector_type(8)));
typedef unsigned short u16x8 __attribute__((ext_vector_type(8)));

// problem sizes
#define NIMG 32
#define CIN  256
#define HWIN 3136      // 56*56
#define COUT 256
#define HWOUT 2916     // 54*54
#define NPOS 93312     // 32*2916 = 729*128

// workspace layout
#define XT_BYTES   ((size_t)NIMG*HWIN*CIN*2)            // 51,380,224
#define WT_OFF     (XT_BYTES + 8192)
#define WT_BYTES   ((size_t)36*256*64*2)                // 1,179,648
#define WS_NEED    (WT_OFF + WT_BYTES)

static __device__ __forceinline__ unsigned short f2bf(float f) {
    union { float f; uint32_t u; } v; v.f = f;
    return (unsigned short)((v.u + 0x7FFFu + ((v.u >> 16) & 1u)) >> 16);
}

static __device__ __forceinline__ void gload16(const void* g, void* l) {
    __builtin_amdgcn_global_load_lds(
        (const __attribute__((address_space(1))) void*)g,
        (__attribute__((address_space(3))) void*)l, 16, 0, 0);
}

static __device__ __forceinline__ uint32_t lds_a(const void* p) {
    return (uint32_t)(uintptr_t)(__attribute__((address_space(3))) const void*)p;
}

static __device__ __forceinline__ u16x8 ldsr(uint32_t addr) {
    u16x8 r;
    asm volatile("ds_read_b128 %0, %1" : "=v"(r) : "v"(addr));
    return r;
}

#define BAR()   __builtin_amdgcn_s_barrier()
#define LGKM0() do { asm volatile("s_waitcnt lgkmcnt(0)" ::: "memory"); \
                     __builtin_amdgcn_sched_barrier(0); } while (0)
#define VM12()  asm volatile("s_waitcnt vmcnt(12)" ::: "memory")
#define VM6()   asm volatile("s_waitcnt vmcnt(6)" ::: "memory")
#define VM0()   asm volatile("s_waitcnt vmcnt(0)" ::: "memory")
#define PRIO1() __builtin_amdgcn_s_setprio(1)
#define PRIO0() __builtin_amdgcn_s_setprio(0)

#define MF(a_, b_, c_) __builtin_amdgcn_mfma_f32_16x16x32_bf16( \
    __builtin_bit_cast(bf16x8, a_), __builtin_bit_cast(bf16x8, b_), c_, 0, 0, 0)

// ---- W transform: [o][c][3][3] f32 -> bf16 +-1, blocked [kt=k9*4+cc][256 o][64 c]
__global__ void wxform(const float* __restrict__ W, unsigned short* __restrict__ Wt) {
    int idx = blockIdx.x * 256 + threadIdx.x;   // 589824 total
    int c6 = idx & 63;
    int o  = (idx >> 6) & 255;
    int cc = (idx >> 14) & 3;
    int k9 = idx >> 16;
    int c = cc * 64 + c6;
    float w = W[(size_t)(o * 256 + c) * 9 + k9];
    Wt[idx] = (w >= 0.0f) ? (unsigned short)0x3F80 : (unsigned short)0xBF80;
}

// ---- X transform: [n][c][56][56] f32 -> [n][hw][c] bf16 (NHWC)
__global__ void xxform(const float* __restrict__ X, unsigned short* __restrict__ Xt) {
    __shared__ float tile[32][65];
    int bid = blockIdx.x;
    int hwc = bid % 49;
    int cc  = (bid / 49) & 7;
    int n   = bid / (49 * 8);
    int hw0 = hwc * 64;
    int c0  = cc * 32;
    int t = threadIdx.x;
    {
        int c = t >> 3;
        int w = (t & 7) * 8;
        const float* src = X + (size_t)(n * CIN + c0 + c) * HWIN + hw0 + w;
        float4 a = *(const float4*)src;
        float4 b = *(const float4*)(src + 4);
        tile[c][w + 0] = a.x; tile[c][w + 1] = a.y; tile[c][w + 2] = a.z; tile[c][w + 3] = a.w;
        tile[c][w + 4] = b.x; tile[c][w + 5] = b.y; tile[c][w + 6] = b.z; tile[c][w + 7] = b.w;
    }
    __syncthreads();
    {
        int w  = t >> 2;
        int cb = (t & 3) * 8;
        u16x8 v;
        #pragma unroll
        for (int j = 0; j < 8; ++j) v[j] = f2bf(tile[cb + j][w]);
        *(u16x8*)(Xt + (size_t)(n * HWIN + hw0 + w) * 256 + c0 + cb) = v;
    }
}

// ---- triple-buffered implicit GEMM: out[o][P] = sum_k Wb[o][k] * X[P][k]
// BM=256 (all o), BN=128 (pos), BK=64; 512 thr = 8 waves (2M x 4N), wave tile 128x32
// LDS: 3 bufs x (A 32KB + B 16KB) = 144KB; 1 phase per K-tile (32 MFMA/wave);
// vmcnt(6) counted (never drains in main loop); XOR (row&7) swizzle both-sides
__global__ __launch_bounds__(512, 2)
void bconv_gemm(const unsigned short* __restrict__ Xt,
                const unsigned short* __restrict__ Wt,
                float* __restrict__ out) {
    __shared__ __align__(16) char smem[147456];

    const int t    = threadIdx.x;
    const int wid  = t >> 6;
    const int lane = t & 63;
    const int l15  = lane & 15;
    const int lg   = lane >> 4;
    const int wr   = wid >> 2;       // 0..1 (M)
    const int wc   = wid & 3;        // 0..3 (N)
    const uint32_t P0 = blockIdx.x * 128u;

    // staging constants (XOR swizzle baked into the GLOBAL source column)
    const uint32_t colxB = (uint32_t)(((t & 7) ^ ((t >> 3) & 7)) << 4);  // bytes
    const uint32_t rowt  = (uint32_t)(t >> 3);                           // 0..63

    // A per-thread byte base (row rowt + r*64, swizzled col)
    const char* pA0 = (const char*)Wt + rowt * 128 + colxB;

    // B gather byte bases: 2 rows per thread (r*64 + rowt)
    const char* bB[2];
    #pragma unroll
    for (int r = 0; r < 2; ++r) {
        uint32_t pos = P0 + (uint32_t)(r * 64) + rowt;
        uint32_t ni = pos / (uint32_t)HWOUT;
        uint32_t rm = pos - ni * HWOUT;
        uint32_t ph = rm / 54u;
        uint32_t pw = rm - ph * 54u;
        bB[r] = (const char*)Xt + (size_t)(ni * HWIN + ph * 56u + pw) * 512 + colxB;
    }

    // ds_read offsets (swizzled read side)
    const uint32_t x7  = (uint32_t)(l15 & 7);
    const uint32_t ck0 = ((((uint32_t)lg) ^ x7) << 4);
    const uint32_t ck1 = (((4u | (uint32_t)lg) ^ x7) << 4);
    uint32_t arow[8], brow[2];
    #pragma unroll
    for (int m = 0; m < 8; ++m) arow[m] = (uint32_t)(wr * 128 + m * 16 + l15) * 128u;
    #pragma unroll
    for (int n = 0; n < 2; ++n) brow[n] = 32768u + (uint32_t)(wc * 32 + n * 16 + l15) * 128u;

    const uint32_t L0 = lds_a(smem);

    f32x4 acc[8][2];
    #pragma unroll
    for (int m = 0; m < 8; ++m)
        #pragma unroll
        for (int n = 0; n < 2; ++n)
            acc[m][n] = (f32x4){0.f, 0.f, 0.f, 0.f};

    // B-staging k-offset tracker: koff = khw*512 + cc*128 for tile being staged
    uint32_t cc3 = 3, k3 = 0, koff = 384;   // tracks tile kt+3, starts at tile 3

    auto STAGE = [&](uint32_t off, int ktp3, uint32_t kof) {
        const char* p = pA0 + (size_t)ktp3 * 32768u;
        #pragma unroll
        for (int r = 0; r < 4; ++r)
            gload16(p + r * 8192, smem + off + r * 8192 + (size_t)t * 16);
        #pragma unroll
        for (int r = 0; r < 2; ++r)
            gload16(bB[r] + kof, smem + off + 32768 + r * 8192 + (size_t)t * 16);
    };

    // prologue: tiles 0,1,2 -> bufs 0,1,2
    STAGE(0u, 0, 0u);
    STAGE(49152u, 1, 128u);
    STAGE(98304u, 2, 256u);
    VM12();   // certify tile 0 (oldest 6)
    BAR();

    // PHASE: mode 0 = stage kt+3 + VM6; 1 = no stage, VM6; 2 = no stage, VM0
    auto PHASE = [&](uint32_t off, int kt, int mode) {
        u16x8 A0[8], A1[8], F0[2], F1[2];
        const uint32_t base = L0 + off;
        #pragma unroll
        for (int m = 0; m < 8; ++m) {
            A0[m] = ldsr(base + arow[m] + ck0);
            A1[m] = ldsr(base + arow[m] + ck1);
        }
        #pragma unroll
        for (int n = 0; n < 2; ++n) {
            F0[n] = ldsr(base + brow[n] + ck0);
            F1[n] = ldsr(base + brow[n] + ck1);
        }
        if (mode == 2) { VM0(); } else { VM6(); }   // certify NEXT phase's buffer
        LGKM0();
        BAR();                                       // all reads of this buf done
        if (mode == 0) {
            STAGE(off, kt + 3, koff);
            // advance tracker to next staged tile
            if (cc3 == 3) { cc3 = 0; koff += ((k3 == 2) ? 54u : 1u) * 512u - 384u; k3 = (k3 == 2) ? 0u : k3 + 1u; }
            else          { cc3++; koff += 128u; }
        }
        PRIO1();
        #pragma unroll
        for (int m = 0; m < 8; ++m) {
            acc[m][0] = MF(A0[m], F0[0], acc[m][0]);
            acc[m][1] = MF(A0[m], F0[1], acc[m][1]);
        }
        #pragma unroll
        for (int m = 0; m < 8; ++m) {
            acc[m][0] = MF(A1[m], F1[0], acc[m][0]);
            acc[m][1] = MF(A1[m], F1[1], acc[m][1]);
        }
        PRIO0();
    };

    int kt = 0;
    for (int g = 0; g < 11; ++g) {      // kt = 0..32 staged (stages tiles 3..35)
        PHASE(0u, kt, 0); ++kt;
        PHASE(49152u, kt, 0); ++kt;
        PHASE(98304u, kt, 0); ++kt;
    }
    PHASE(0u, 33, 1);       // VM6 certifies tile 34
    PHASE(49152u, 34, 2);   // VM0 certifies tile 35
    PHASE(98304u, 35, 2);

    // epilogue: C/D col = l15 -> P, row = lg*4+r -> o   (93312 = 729*128 exact)
    #pragma unroll
    for (int n = 0; n < 2; ++n) {
        uint32_t P = P0 + (uint32_t)(wc * 32 + n * 16 + l15);
        uint32_t ni = P / (uint32_t)HWOUT;
        uint32_t rm = P - ni * HWOUT;
        float* ob_ = out + (size_t)(ni * 256u) * HWOUT + rm;
        #pragma unroll
        for (int m = 0; m < 8; ++m) {
            #pragma unroll
            for (int r = 0; r < 4; ++r)
                ob_[(size_t)(wr * 128 + m * 16 + lg * 4 + r) * HWOUT] = acc[m][n][r];
        }
    }
}

// ---- slow correct fallback (only if ws too small)
__global__ void bconv_fallback(const float* __restrict__ X, const float* __restrict__ W,
                               float* __restrict__ out) {
    size_t idx = (size_t)blockIdx.x * 256 + threadIdx.x;
    int ow = (int)(idx % 54);
    int oh = (int)((idx / 54) % 54);
    int o  = (int)((idx / 2916) % 256);
    int n  = (int)(idx / 746496);
    float s = 0.f;
    for (int c = 0; c < 256; ++c) {
        const float* xr = X + ((size_t)(n * 256 + c) * 56 + oh) * 56 + ow;
        const float* wr = W + (size_t)(o * 256 + c) * 9;
        #pragma unroll
        for (int kh = 0; kh < 3; ++kh)
            #pragma unroll
            for (int kw = 0; kw < 3; ++kw) {
                float w = wr[kh * 3 + kw];
                float x = xr[kh * 56 + kw];
                s += (w >= 0.f) ? x : -x;
            }
    }
    out[idx] = s;
}

extern "C" void kernel_launch(void* const* d_in, const int* in_sizes, int n_in,
                              void* d_out, int out_size, void* d_ws, size_t ws_size,
                              hipStream_t stream) {
    const float* X = (const float*)d_in[0];
    const float* W = (const float*)d_in[1];
    float* out = (float*)d_out;

    if (ws_size < WS_NEED) {
        bconv_fallback<<<93312, 256, 0, stream>>>(X, W, out);
        return;
    }
    unsigned short* Xt = (unsigned short*)d_ws;
    unsigned short* Wt = (unsigned short*)((char*)d_ws + WT_OFF);

    wxform<<<2304, 256, 0, stream>>>(W, Wt);
    xxform<<<12544, 256, 0, stream>>>(X, Xt);

    bconv_gemm<<<729, 512, 0, stream>>>(Xt, Wt, out);
}